// Round 14
// baseline (2268.456 us; speedup 1.0000x reference)
//
#include <hip/hip_runtime.h>
#include <math.h>

#define BB 2
#define VV 4
#define NPTSC 65536
#define HH 256
#define WW 256

typedef __attribute__((ext_vector_type(8))) unsigned short ushort8;
typedef __attribute__((ext_vector_type(8))) __bf16 bf16x8;
typedef __attribute__((ext_vector_type(4))) float floatx4;

__device__ __forceinline__ float b2f(unsigned short u) {
  unsigned int x = ((unsigned int)u) << 16;
  return __builtin_bit_cast(float, x);
}
__device__ __forceinline__ unsigned short f2b(float f) {
  unsigned int x = __builtin_bit_cast(unsigned int, f);
  x = x + 0x7fffu + ((x >> 16) & 1u);
  return (unsigned short)(x >> 16);
}

// MFMA MLP layer; A from LDS (bf16), W read strided from original f32 [K][128].
// Layouts (m89/m120): A[m=lane&15][k=quad*8+j]; B[n=lane&15][k=quad*8+j];
// C/D: col=lane&15, row=quad*4+reg.
// MODE 0: relu+store; MODE 1: relu+residual+store; MODE 2: accumulate to racc.
template<int K, int MODE>
__device__ __forceinline__ void mlp_layer_g(
    const unsigned short* A, int lda,
    const float* __restrict__ Wg, int kreal,
    const float* __restrict__ bias,          // LDS f32
    const unsigned short* Res, int ldr,
    unsigned short* Dst, int ldd,
    float* racc, int lane)
{
  constexpr int NK = K / 32;
  const int col = lane & 15, quad = lane >> 4;
  ushort8 a[2][NK];
#pragma unroll
  for (int mt = 0; mt < 2; ++mt)
#pragma unroll
    for (int kk = 0; kk < NK; ++kk)
      a[mt][kk] = *(const ushort8*)(A + (mt * 16 + col) * lda + kk * 32 + quad * 8);
#pragma unroll
  for (int nt = 0; nt < 8; ++nt) {
    const int n = nt * 16 + col;
    ushort8 bfr[NK];
#pragma unroll
    for (int kk = 0; kk < NK; ++kk)
#pragma unroll
      for (int j = 0; j < 8; ++j) {
        int k = kk * 32 + quad * 8 + j;
        float wv = (k < kreal) ? Wg[k * 128 + n] : 0.f;
        bfr[kk][j] = f2b(wv);
      }
    float bsc = bias[n];
#pragma unroll
    for (int mt = 0; mt < 2; ++mt) {
      floatx4 acc = {0.f, 0.f, 0.f, 0.f};
#pragma unroll
      for (int kk = 0; kk < NK; ++kk)
        acc = __builtin_amdgcn_mfma_f32_16x16x32_bf16(
            __builtin_bit_cast(bf16x8, a[mt][kk]),
            __builtin_bit_cast(bf16x8, bfr[kk]), acc, 0, 0, 0);
#pragma unroll
      for (int r = 0; r < 4; ++r) {
        int row = mt * 16 + quad * 4 + r;
        float v = acc[r] + bsc;
        if constexpr (MODE == 2) {
          racc[(mt * 8 + nt) * 4 + r] += v;
        } else {
          if constexpr (MODE == 1) v += b2f(Res[row * ldr + n]);
          v = fmaxf(v, 0.f);
          Dst[row * ldd + n] = f2b(v);
        }
      }
    }
  }
  __syncthreads();
}

// ONE kernel: conv-on-the-fly sampling + PE + view MLP x4 + mean + global MLP.
// grid 2048 x 128 threads (2 waves x 32 points). f32 in, f32 out.
// No statics, no workspace, LDS = 50 KiB.
__global__ __launch_bounds__(128) void mvct_r14(
    const float* __restrict__ views, const float* __restrict__ angles,
    const int* __restrict__ idx,
    const float* __restrict__ conv_w, const float* __restrict__ conv_b,
    const float* __restrict__ vw_in, const float* __restrict__ vb_in,
    const float* __restrict__ vw1, const float* __restrict__ vb1,
    const float* __restrict__ vw2, const float* __restrict__ vb2,
    const float* __restrict__ vw_out, const float* __restrict__ vb_out,
    const float* __restrict__ gw_in, const float* __restrict__ gb_in,
    const float* __restrict__ gw1, const float* __restrict__ gb1,
    const float* __restrict__ gw2, const float* __restrict__ gb2,
    const float* __restrict__ gw_out, const float* __restrict__ gb_out,
    float* __restrict__ out)
{
  __shared__ __align__(16) unsigned short sX[2][32][168];  // xin(160)/t(128)
  __shared__ __align__(16) unsigned short sH[2][32][136];  // h
  __shared__ float sCW[1152];   // conv_w [128][9]
  __shared__ float sCB[128];    // conv_b
  __shared__ float sBias[1664]; // vb_in|vb1*3|vb2*3|vb_out|gb_in|gb1*2|gb2*2
  __shared__ float sGWo[128];   // gw_out

  const int tid = threadIdx.x;
  const int wv = tid >> 6, lane = tid & 63;
  const int b = blockIdx.x >> 10;
  const int pts0 = (blockIdx.x & 1023) * 64 + wv * 32;

  unsigned short (*X)[168] = sX[wv];
  unsigned short (*Hb)[136] = sH[wv];

  // stage conv weights / biases / gw_out into LDS
  for (int i = tid; i < 1152; i += 128) sCW[i] = conv_w[i];
  if (tid < 128) { sCB[tid] = conv_b[tid]; sGWo[tid] = gw_out[tid]; }
  for (int i = tid; i < 1664; i += 128) {
    float v;
    if (i < 128)        v = vb_in[i];
    else if (i < 512)   v = vb1[i - 128];
    else if (i < 896)   v = vb2[i - 512];
    else if (i < 1024)  v = vb_out[i - 896];
    else if (i < 1152)  v = gb_in[i - 1024];
    else if (i < 1408)  v = gb1[i - 1152];
    else                v = gb2[i - 1408];
    sBias[i] = v;
  }

  const float inv = 2.0f / 127.0f;
  const int pl = lane >> 4, cg = lane & 15;

  // PE into X cols 128..159 (cols never clobbered by the layer loop)
  if (lane < 32) {
    int id = idx[pts0 + lane];
    int iz = (id >> 14) & 127, iy = (id >> 7) & 127, ix = id & 127;
    float x = ix * inv - 1.f, y = iy * inv - 1.f, z = iz * inv - 1.f;
    const float PI = 3.14159265358979323846f;
    float pe[9] = {z, y, x, sinf(PI * z), sinf(PI * y), sinf(PI * x),
                   cosf(PI * z), cosf(PI * y), cosf(PI * x)};
#pragma unroll
    for (int j = 0; j < 9; ++j) X[lane][128 + j] = f2b(pe[j]);
    for (int j = 137; j < 160; ++j) X[lane][j] = 0;
  }
  __syncthreads();

  float racc[64];
#pragma unroll
  for (int i = 0; i < 64; ++i) racc[i] = 0.f;

#pragma unroll 1
  for (int v = 0; v < VV; ++v) {
    const int bv = b * VV + v;
    const float ang = angles[bv];
    const float ct = cosf(ang), st = sinf(ang);
    const float* img = views + (size_t)bv * HH * WW;

    // conv(3x3,1->128,SAME,relu) at 4 corner pixels + bilinear, 32 pts
    for (int it = 0; it < 8; ++it) {
      int lp = it * 4 + pl;
      int id = idx[pts0 + lp];
      int iz = (id >> 14) & 127, iy = (id >> 7) & 127, ix = id & 127;
      float x = ix * inv - 1.f, y = iy * inv - 1.f, z = iz * inv - 1.f;
      float u = x * ct - y * st;
      float px = (u + 1.f) * 127.5f, py = (z + 1.f) * 127.5f;
      px = fminf(fmaxf(px, 0.f), 255.f);
      py = fminf(fmaxf(py, 0.f), 255.f);
      int x0 = min((int)px, 254), y0 = min((int)py, 254);
      float wx = px - (float)x0, wy = py - (float)y0;
      float t[4][4];
#pragma unroll
      for (int r = 0; r < 4; ++r) {
        int ty = y0 - 1 + r;
#pragma unroll
        for (int d = 0; d < 4; ++d) {
          int tx = x0 - 1 + d;
          bool ok = (ty >= 0) & (ty < HH) & (tx >= 0) & (tx < WW);
          t[r][d] = ok ? img[ty * WW + tx] : 0.f;
        }
      }
      float w00 = (1.f - wx) * (1.f - wy), w01 = wx * (1.f - wy);
      float w10 = (1.f - wx) * wy, w11 = wx * wy;
      ushort8 o;
#pragma unroll
      for (int j = 0; j < 8; ++j) {
        int c = cg * 8 + j;
        const float* wr = &sCW[c * 9];
        float cb = sCB[c];
        float f00 = cb, f01 = cb, f10 = cb, f11 = cb;
#pragma unroll
        for (int r = 0; r < 3; ++r)
#pragma unroll
          for (int d = 0; d < 3; ++d) {
            float wgt = wr[r * 3 + d];
            f00 += t[r][d] * wgt;
            f01 += t[r][d + 1] * wgt;
            f10 += t[r + 1][d] * wgt;
            f11 += t[r + 1][d + 1] * wgt;
          }
        f00 = fmaxf(f00, 0.f); f01 = fmaxf(f01, 0.f);
        f10 = fmaxf(f10, 0.f); f11 = fmaxf(f11, 0.f);
        o[j] = f2b(w00 * f00 + w01 * f01 + w10 * f10 + w11 * f11);
      }
      *(ushort8*)&X[lp][cg * 8] = o;
    }
    __syncthreads();

    mlp_layer_g<160, 0>(&X[0][0], 168, vw_in, 137, sBias + 0,
                        nullptr, 0, &Hb[0][0], 136, nullptr, lane);
#pragma unroll 1
    for (int i = 0; i < 3; ++i) {
      mlp_layer_g<128, 0>(&Hb[0][0], 136, vw1 + i * 16384, 128,
                          sBias + 128 + i * 128,
                          nullptr, 0, &X[0][0], 168, nullptr, lane);
      mlp_layer_g<128, 1>(&X[0][0], 168, vw2 + i * 16384, 128,
                          sBias + 512 + i * 128,
                          &Hb[0][0], 136, &Hb[0][0], 136, nullptr, lane);
    }
    mlp_layer_g<128, 2>(&Hb[0][0], 136, vw_out, 128, sBias + 896,
                        nullptr, 0, nullptr, 0, racc, lane);
  }

  // mean over views -> X cols 0..127 (bf16)
  {
    const int col = lane & 15, quad = lane >> 4;
#pragma unroll
    for (int mt = 0; mt < 2; ++mt)
#pragma unroll
      for (int nt = 0; nt < 8; ++nt)
#pragma unroll
        for (int r = 0; r < 4; ++r)
          X[mt * 16 + quad * 4 + r][nt * 16 + col] =
              f2b(racc[(mt * 8 + nt) * 4 + r] * 0.25f);
  }
  __syncthreads();

  mlp_layer_g<128, 0>(&X[0][0], 168, gw_in, 128, sBias + 1024,
                      nullptr, 0, &Hb[0][0], 136, nullptr, lane);
#pragma unroll 1
  for (int i = 0; i < 2; ++i) {
    mlp_layer_g<128, 0>(&Hb[0][0], 136, gw1 + i * 16384, 128,
                        sBias + 1152 + i * 128,
                        nullptr, 0, &X[0][0], 168, nullptr, lane);
    mlp_layer_g<128, 1>(&X[0][0], 168, gw2 + i * 16384, 128,
                        sBias + 1408 + i * 128,
                        &Hb[0][0], 136, &Hb[0][0], 136, nullptr, lane);
  }

  // out = h @ gw_out + gb_out; 2 lanes per point; FLOAT32 output
  const int p = lane & 31, half = lane >> 5;
  float s = 0.f;
  const unsigned short* hr = &Hb[p][half * 64];
#pragma unroll
  for (int c = 0; c < 64; ++c)
    s += b2f(hr[c]) * sGWo[half * 64 + c];
  s += __shfl_xor(s, 32, 64);
  if (half == 0)
    out[(size_t)b * NPTSC + pts0 + p] = s + gb_out[0];
}

extern "C" void kernel_launch(void* const* d_in, const int* in_sizes, int n_in,
                              void* d_out, int out_size, void* d_ws, size_t ws_size,
                              hipStream_t stream) {
  const float* views  = (const float*)d_in[0];
  const float* angles = (const float*)d_in[1];
  const int*   idx    = (const int*)d_in[2];
  const float* conv_w = (const float*)d_in[3];
  const float* conv_b = (const float*)d_in[4];
  const float* vw_in  = (const float*)d_in[5];
  const float* vb_in  = (const float*)d_in[6];
  const float* vw1    = (const float*)d_in[7];
  const float* vb1    = (const float*)d_in[8];
  const float* vw2    = (const float*)d_in[9];
  const float* vb2    = (const float*)d_in[10];
  const float* vw_out = (const float*)d_in[11];
  const float* vb_out = (const float*)d_in[12];
  const float* gw_in  = (const float*)d_in[13];
  const float* gb_in  = (const float*)d_in[14];
  const float* gw1    = (const float*)d_in[15];
  const float* gb1    = (const float*)d_in[16];
  const float* gw2    = (const float*)d_in[17];
  const float* gb2    = (const float*)d_in[18];
  const float* gw_out = (const float*)d_in[19];
  const float* gb_out = (const float*)d_in[20];

  hipLaunchKernelGGL(mvct_r14, dim3(BB * (NPTSC / 64)), dim3(128), 0, stream,
                     views, angles, idx, conv_w, conv_b,
                     vw_in, vb_in, vw1, vb1, vw2, vb2, vw_out, vb_out,
                     gw_in, gb_in, gw1, gb1, gw2, gb2, gw_out, gb_out,
                     (float*)d_out);
}

// Round 15
// 869.687 us; speedup vs baseline: 2.6084x; 2.6084x over previous
//
#include <hip/hip_runtime.h>
#include <math.h>

#define BB 2
#define VV 4
#define NPTSC 65536
#define HH 256
#define WW 256

typedef __attribute__((ext_vector_type(8))) unsigned short ushort8;
typedef __attribute__((ext_vector_type(8))) __bf16 bf16x8;
typedef __attribute__((ext_vector_type(4))) float floatx4;

__device__ __forceinline__ float b2f(unsigned short u) {
  unsigned int x = ((unsigned int)u) << 16;
  return __builtin_bit_cast(float, x);
}
__device__ __forceinline__ unsigned short f2b(float f) {
  unsigned int x = __builtin_bit_cast(unsigned int, f);
  x = x + 0x7fffu + ((x >> 16) & 1u);
  return (unsigned short)(x >> 16);
}

// ---- prep: f32 weights -> bf16 [out][in] into d_ws -------------------------
// layout (u16 elems): w_in_t[128][160]@0 (K padded 137->160 with zeros),
// vw1_t 3x[128][128]@20480, vw2_t 3x@69632, vw_out_t@118784, gw_in_t@135168,
// gw1_t 2x@151552, gw2_t 2x@184320; total 217088 (434 KB).
__global__ __launch_bounds__(256) void mvct_prep(
    const float* __restrict__ vw_in, const float* __restrict__ vw1,
    const float* __restrict__ vw2, const float* __restrict__ vw_out,
    const float* __restrict__ gw_in, const float* __restrict__ gw1,
    const float* __restrict__ gw2, unsigned short* __restrict__ wbuf)
{
  int tid = blockIdx.x * 256 + threadIdx.x;
  if (tid >= 217088) return;
  float val;
  if (tid < 20480) {
    int n = tid / 160, k = tid - n * 160;
    val = (k < 137) ? vw_in[k * 128 + n] : 0.f;
  } else {
    int t = tid - 20480;
    const float* src;
    if (t < 49152) { src = vw1; }
    else if (t < 98304) { t -= 49152; src = vw2; }
    else if (t < 114688) { t -= 98304; src = vw_out; }
    else if (t < 131072) { t -= 114688; src = gw_in; }
    else if (t < 163840) { t -= 131072; src = gw1; }
    else { t -= 163840; src = gw2; }
    int i = t >> 14; int r = t & 16383; int n = r >> 7; int k = r & 127;
    val = src[i * 16384 + k * 128 + n];
  }
  wbuf[tid] = f2b(val);
}

// ---- MFMA MLP layer; A from LDS bf16, Wt = preconverted bf16 [128][K] ------
// Layouts (m89/m120): A[m=lane&15][k=quad*8+j]; B[n=lane&15][k=quad*8+j];
// C/D: col=lane&15, row=quad*4+reg.
// MODE 0: relu+store; MODE 1: relu+residual+store; MODE 2: accumulate to racc.
template<int K, int MODE>
__device__ __forceinline__ void mlp_layer(
    const unsigned short* A, int lda,
    const unsigned short* __restrict__ Wt,
    const float* __restrict__ bias,          // LDS f32
    const unsigned short* Res, int ldr,
    unsigned short* Dst, int ldd,
    float* racc, int lane)
{
  constexpr int NK = K / 32;
  const int col = lane & 15, quad = lane >> 4;
  ushort8 a[2][NK];
#pragma unroll
  for (int mt = 0; mt < 2; ++mt)
#pragma unroll
    for (int kk = 0; kk < NK; ++kk)
      a[mt][kk] = *(const ushort8*)(A + (mt * 16 + col) * lda + kk * 32 + quad * 8);
#pragma unroll
  for (int nt = 0; nt < 8; ++nt) {
    const int n = nt * 16 + col;
    ushort8 bfr[NK];
#pragma unroll
    for (int kk = 0; kk < NK; ++kk)
      bfr[kk] = *(const ushort8*)(Wt + n * K + kk * 32 + quad * 8);
    float bsc = bias[n];
#pragma unroll
    for (int mt = 0; mt < 2; ++mt) {
      floatx4 acc = {0.f, 0.f, 0.f, 0.f};
#pragma unroll
      for (int kk = 0; kk < NK; ++kk)
        acc = __builtin_amdgcn_mfma_f32_16x16x32_bf16(
            __builtin_bit_cast(bf16x8, a[mt][kk]),
            __builtin_bit_cast(bf16x8, bfr[kk]), acc, 0, 0, 0);
#pragma unroll
      for (int r = 0; r < 4; ++r) {
        int row = mt * 16 + quad * 4 + r;
        float v = acc[r] + bsc;
        if constexpr (MODE == 2) {
          racc[(mt * 8 + nt) * 4 + r] += v;
        } else {
          if constexpr (MODE == 1) v += b2f(Res[row * ldr + n]);
          v = fmaxf(v, 0.f);
          Dst[row * ldd + n] = f2b(v);
        }
      }
    }
  }
  __syncthreads();
}

// ---- main: conv-on-the-fly + PE + view MLP x4 + mean + global MLP ----------
// grid 2048 x 128 threads (2 waves x 32 points). f32 in, f32 out.
__global__ __launch_bounds__(128) void mvct_main(
    const float* __restrict__ views, const float* __restrict__ angles,
    const int* __restrict__ idx,
    const float* __restrict__ conv_w, const float* __restrict__ conv_b,
    const unsigned short* __restrict__ wbuf,
    const float* __restrict__ vb_in, const float* __restrict__ vb1,
    const float* __restrict__ vb2, const float* __restrict__ vb_out,
    const float* __restrict__ gb_in, const float* __restrict__ gb1,
    const float* __restrict__ gb2, const float* __restrict__ gw_out,
    const float* __restrict__ gb_out,
    float* __restrict__ out)
{
  __shared__ __align__(16) unsigned short sX[2][32][168];  // xin(160)/t(128)
  __shared__ __align__(16) unsigned short sH[2][32][136];  // h
  __shared__ float sCW[1152];   // conv_w [128][9]
  __shared__ float sCB[128];    // conv_b
  __shared__ float sBias[1664]; // vb_in|vb1*3|vb2*3|vb_out|gb_in|gb1*2|gb2*2
  __shared__ float sGWo[128];   // gw_out

  const int tid = threadIdx.x;
  const int wv = tid >> 6, lane = tid & 63;
  const int b = blockIdx.x >> 10;
  const int pts0 = (blockIdx.x & 1023) * 64 + wv * 32;

  unsigned short (*X)[168] = sX[wv];
  unsigned short (*Hb)[136] = sH[wv];

  for (int i = tid; i < 1152; i += 128) sCW[i] = conv_w[i];
  if (tid < 128) { sCB[tid] = conv_b[tid]; sGWo[tid] = gw_out[tid]; }
  for (int i = tid; i < 1664; i += 128) {
    float v;
    if (i < 128)        v = vb_in[i];
    else if (i < 512)   v = vb1[i - 128];
    else if (i < 896)   v = vb2[i - 512];
    else if (i < 1024)  v = vb_out[i - 896];
    else if (i < 1152)  v = gb_in[i - 1024];
    else if (i < 1408)  v = gb1[i - 1152];
    else                v = gb2[i - 1408];
    sBias[i] = v;
  }

  const unsigned short* w_in_t   = wbuf;
  const unsigned short* vw1_t    = wbuf + 20480;
  const unsigned short* vw2_t    = wbuf + 69632;
  const unsigned short* vw_out_t = wbuf + 118784;
  const unsigned short* gw_in_t  = wbuf + 135168;
  const unsigned short* gw1_t    = wbuf + 151552;
  const unsigned short* gw2_t    = wbuf + 184320;

  const float inv = 2.0f / 127.0f;
  const int pl = lane >> 4, cg = lane & 15;

  // PE into X cols 128..159 (never clobbered by the layer loop)
  if (lane < 32) {
    int id = idx[pts0 + lane];
    int iz = (id >> 14) & 127, iy = (id >> 7) & 127, ix = id & 127;
    float x = ix * inv - 1.f, y = iy * inv - 1.f, z = iz * inv - 1.f;
    const float PI = 3.14159265358979323846f;
    float pe[9] = {z, y, x, sinf(PI * z), sinf(PI * y), sinf(PI * x),
                   cosf(PI * z), cosf(PI * y), cosf(PI * x)};
#pragma unroll
    for (int j = 0; j < 9; ++j) X[lane][128 + j] = f2b(pe[j]);
    for (int j = 137; j < 160; ++j) X[lane][j] = 0;
  }
  __syncthreads();

  float racc[64];
#pragma unroll
  for (int i = 0; i < 64; ++i) racc[i] = 0.f;

#pragma unroll 1
  for (int v = 0; v < VV; ++v) {
    const int bv = b * VV + v;
    const float ang = angles[bv];
    const float ct = cosf(ang), st = sinf(ang);
    const float* img = views + (size_t)bv * HH * WW;

    // conv(3x3,1->128,SAME,relu) at 4 corner pixels + bilinear, 32 pts
    for (int it = 0; it < 8; ++it) {
      int lp = it * 4 + pl;
      int id = idx[pts0 + lp];
      int iz = (id >> 14) & 127, iy = (id >> 7) & 127, ix = id & 127;
      float x = ix * inv - 1.f, y = iy * inv - 1.f, z = iz * inv - 1.f;
      float u = x * ct - y * st;
      float px = (u + 1.f) * 127.5f, py = (z + 1.f) * 127.5f;
      px = fminf(fmaxf(px, 0.f), 255.f);
      py = fminf(fmaxf(py, 0.f), 255.f);
      int x0 = min((int)px, 254), y0 = min((int)py, 254);
      float wx = px - (float)x0, wy = py - (float)y0;
      float t[4][4];
#pragma unroll
      for (int r = 0; r < 4; ++r) {
        int ty = y0 - 1 + r;
#pragma unroll
        for (int d = 0; d < 4; ++d) {
          int tx = x0 - 1 + d;
          bool ok = (ty >= 0) & (ty < HH) & (tx >= 0) & (tx < WW);
          t[r][d] = ok ? img[ty * WW + tx] : 0.f;
        }
      }
      float w00 = (1.f - wx) * (1.f - wy), w01 = wx * (1.f - wy);
      float w10 = (1.f - wx) * wy, w11 = wx * wy;
      ushort8 o;
#pragma unroll
      for (int j = 0; j < 8; ++j) {
        int c = cg * 8 + j;
        const float* wr = &sCW[c * 9];
        float cb = sCB[c];
        float f00 = cb, f01 = cb, f10 = cb, f11 = cb;
#pragma unroll
        for (int r = 0; r < 3; ++r)
#pragma unroll
          for (int d = 0; d < 3; ++d) {
            float wgt = wr[r * 3 + d];
            f00 += t[r][d] * wgt;
            f01 += t[r][d + 1] * wgt;
            f10 += t[r + 1][d] * wgt;
            f11 += t[r + 1][d + 1] * wgt;
          }
        f00 = fmaxf(f00, 0.f); f01 = fmaxf(f01, 0.f);
        f10 = fmaxf(f10, 0.f); f11 = fmaxf(f11, 0.f);
        o[j] = f2b(w00 * f00 + w01 * f01 + w10 * f10 + w11 * f11);
      }
      *(ushort8*)&X[lp][cg * 8] = o;
    }
    __syncthreads();

    mlp_layer<160, 0>(&X[0][0], 168, w_in_t, sBias + 0,
                      nullptr, 0, &Hb[0][0], 136, nullptr, lane);
#pragma unroll 1
    for (int i = 0; i < 3; ++i) {
      mlp_layer<128, 0>(&Hb[0][0], 136, vw1_t + i * 16384, sBias + 128 + i * 128,
                        nullptr, 0, &X[0][0], 168, nullptr, lane);
      mlp_layer<128, 1>(&X[0][0], 168, vw2_t + i * 16384, sBias + 512 + i * 128,
                        &Hb[0][0], 136, &Hb[0][0], 136, nullptr, lane);
    }
    mlp_layer<128, 2>(&Hb[0][0], 136, vw_out_t, sBias + 896,
                      nullptr, 0, nullptr, 0, racc, lane);
  }

  // mean over views -> X cols 0..127 (bf16)
  {
    const int col = lane & 15, quad = lane >> 4;
#pragma unroll
    for (int mt = 0; mt < 2; ++mt)
#pragma unroll
      for (int nt = 0; nt < 8; ++nt)
#pragma unroll
        for (int r = 0; r < 4; ++r)
          X[mt * 16 + quad * 4 + r][nt * 16 + col] =
              f2b(racc[(mt * 8 + nt) * 4 + r] * 0.25f);
  }
  __syncthreads();

  mlp_layer<128, 0>(&X[0][0], 168, gw_in_t, sBias + 1024,
                    nullptr, 0, &Hb[0][0], 136, nullptr, lane);
#pragma unroll 1
  for (int i = 0; i < 2; ++i) {
    mlp_layer<128, 0>(&Hb[0][0], 136, gw1_t + i * 16384, sBias + 1152 + i * 128,
                      nullptr, 0, &X[0][0], 168, nullptr, lane);
    mlp_layer<128, 1>(&X[0][0], 168, gw2_t + i * 16384, sBias + 1408 + i * 128,
                      &Hb[0][0], 136, &Hb[0][0], 136, nullptr, lane);
  }

  // out = h @ gw_out + gb_out; 2 lanes per point; f32 output
  const int p = lane & 31, half = lane >> 5;
  float s = 0.f;
  const unsigned short* hr = &Hb[p][half * 64];
#pragma unroll
  for (int c = 0; c < 64; ++c)
    s += b2f(hr[c]) * sGWo[half * 64 + c];
  s += __shfl_xor(s, 32, 64);
  if (half == 0)
    out[(size_t)b * NPTSC + pts0 + p] = s + gb_out[0];
}

extern "C" void kernel_launch(void* const* d_in, const int* in_sizes, int n_in,
                              void* d_out, int out_size, void* d_ws, size_t ws_size,
                              hipStream_t stream) {
  const float* views  = (const float*)d_in[0];
  const float* angles = (const float*)d_in[1];
  const int*   idx    = (const int*)d_in[2];
  const float* conv_w = (const float*)d_in[3];
  const float* conv_b = (const float*)d_in[4];
  const float* vw_in  = (const float*)d_in[5];
  const float* vb_in  = (const float*)d_in[6];
  const float* vw1    = (const float*)d_in[7];
  const float* vb1    = (const float*)d_in[8];
  const float* vw2    = (const float*)d_in[9];
  const float* vb2    = (const float*)d_in[10];
  const float* vw_out = (const float*)d_in[11];
  const float* vb_out = (const float*)d_in[12];
  const float* gw_in  = (const float*)d_in[13];
  const float* gb_in  = (const float*)d_in[14];
  const float* gw1    = (const float*)d_in[15];
  const float* gb1    = (const float*)d_in[16];
  const float* gw2    = (const float*)d_in[17];
  const float* gb2    = (const float*)d_in[18];
  const float* gw_out = (const float*)d_in[19];
  const float* gb_out = (const float*)d_in[20];

  unsigned short* wbuf = (unsigned short*)d_ws;  // 217088 u16 = 434 KB

  hipLaunchKernelGGL(mvct_prep, dim3(848), dim3(256), 0, stream,
                     vw_in, vw1, vw2, vw_out, gw_in, gw1, gw2, wbuf);
  hipLaunchKernelGGL(mvct_main, dim3(BB * (NPTSC / 64)), dim3(128), 0, stream,
                     views, angles, idx, conv_w, conv_b, wbuf,
                     vb_in, vb1, vb2, vb_out, gb_in, gb1, gb2, gw_out, gb_out,
                     (float*)d_out);
}

// Round 16
// 828.505 us; speedup vs baseline: 2.7380x; 1.0497x over previous
//
#include <hip/hip_runtime.h>
#include <math.h>

#define BB 2
#define VV 4
#define NPTSC 65536
#define HH 256
#define WW 256
#define CCH 128

typedef __attribute__((ext_vector_type(8))) unsigned short ushort8;
typedef __attribute__((ext_vector_type(8))) __bf16 bf16x8;
typedef __attribute__((ext_vector_type(4))) float floatx4;

// Static feats buffer (128 MiB) — avoids unknown ws_size; fully rewritten
// every launch by mvct_conv.
__device__ unsigned short g_feats[(size_t)BB * VV * HH * WW * CCH];

__device__ __forceinline__ float b2f(unsigned short u) {
  unsigned int x = ((unsigned int)u) << 16;
  return __builtin_bit_cast(float, x);
}
__device__ __forceinline__ unsigned short f2b(float f) {
  unsigned int x = __builtin_bit_cast(unsigned int, f);
  x = x + 0x7fffu + ((x >> 16) & 1u);
  return (unsigned short)(x >> 16);
}

// ---- prep: f32 weights -> bf16 [out][in] into d_ws (434 KB) ----------------
__global__ __launch_bounds__(256) void mvct_prep(
    const float* __restrict__ vw_in, const float* __restrict__ vw1,
    const float* __restrict__ vw2, const float* __restrict__ vw_out,
    const float* __restrict__ gw_in, const float* __restrict__ gw1,
    const float* __restrict__ gw2, unsigned short* __restrict__ wbuf)
{
  int tid = blockIdx.x * 256 + threadIdx.x;
  if (tid >= 217088) return;
  float val;
  if (tid < 20480) {
    int n = tid / 160, k = tid - n * 160;
    val = (k < 137) ? vw_in[k * 128 + n] : 0.f;
  } else {
    int t = tid - 20480;
    const float* src;
    if (t < 49152) { src = vw1; }
    else if (t < 98304) { t -= 49152; src = vw2; }
    else if (t < 114688) { t -= 98304; src = vw_out; }
    else if (t < 131072) { t -= 114688; src = gw_in; }
    else if (t < 163840) { t -= 131072; src = gw1; }
    else { t -= 163840; src = gw2; }
    int i = t >> 14; int r = t & 16383; int n = r >> 7; int k = r & 127;
    val = src[i * 16384 + k * 128 + n];
  }
  wbuf[tid] = f2b(val);
}

// ---- conv 3x3 SAME, 1->128 ch, relu, channel-last bf16 into g_feats --------
__global__ __launch_bounds__(128) void mvct_conv(
    const float* __restrict__ views, const float* __restrict__ conv_w,
    const float* __restrict__ conv_b)
{
  int bv = blockIdx.x >> 8;
  int y = blockIdx.x & 255;
  int c = threadIdx.x;  // out channel
  float w[9];
#pragma unroll
  for (int j = 0; j < 9; ++j) w[j] = conv_w[c * 9 + j];
  float bias = conv_b[c];

  __shared__ float rows[3][258];
  const float* img = views + (size_t)bv * HH * WW;
#pragma unroll
  for (int r = 0; r < 3; ++r) {
    int yy = y - 1 + r;
    for (int x = c; x < 258; x += 128) {
      int xx = x - 1;
      float v = 0.f;
      if (yy >= 0 && yy < HH && xx >= 0 && xx < WW) v = img[yy * WW + xx];
      rows[r][x] = v;
    }
  }
  __syncthreads();

  unsigned short* orow = g_feats + ((size_t)(bv * HH + y) * WW) * CCH + c;
  for (int x = 0; x < WW; ++x) {
    float acc = bias;
#pragma unroll
    for (int r = 0; r < 3; ++r)
#pragma unroll
      for (int d = 0; d < 3; ++d)
        acc += rows[r][x + d] * w[r * 3 + d];
    acc = fmaxf(acc, 0.f);
    orow[(size_t)x * CCH] = f2b(acc);
  }
}

// ---- MFMA MLP layer; A from LDS bf16, Wt = bf16 [128][K]; bias f32 global --
// Layouts (m89/m120): A[m=lane&15][k=quad*8+j]; B[n=lane&15][k=quad*8+j];
// C/D: col=lane&15, row=quad*4+reg.
// MODE 0: relu+store; MODE 1: relu+residual+store; MODE 2: accumulate to racc.
template<int K, int MODE>
__device__ __forceinline__ void mlp_layer(
    const unsigned short* A, int lda,
    const unsigned short* __restrict__ Wt,
    const float* __restrict__ bias,
    const unsigned short* Res, int ldr,
    unsigned short* Dst, int ldd,
    float* racc, int lane)
{
  constexpr int NK = K / 32;
  const int col = lane & 15, quad = lane >> 4;
  ushort8 a[2][NK];
#pragma unroll
  for (int mt = 0; mt < 2; ++mt)
#pragma unroll
    for (int kk = 0; kk < NK; ++kk)
      a[mt][kk] = *(const ushort8*)(A + (mt * 16 + col) * lda + kk * 32 + quad * 8);
#pragma unroll
  for (int nt = 0; nt < 8; ++nt) {
    const int n = nt * 16 + col;
    ushort8 bfr[NK];
#pragma unroll
    for (int kk = 0; kk < NK; ++kk)
      bfr[kk] = *(const ushort8*)(Wt + n * K + kk * 32 + quad * 8);
    float bsc = bias[n];
#pragma unroll
    for (int mt = 0; mt < 2; ++mt) {
      floatx4 acc = {0.f, 0.f, 0.f, 0.f};
#pragma unroll
      for (int kk = 0; kk < NK; ++kk)
        acc = __builtin_amdgcn_mfma_f32_16x16x32_bf16(
            __builtin_bit_cast(bf16x8, a[mt][kk]),
            __builtin_bit_cast(bf16x8, bfr[kk]), acc, 0, 0, 0);
#pragma unroll
      for (int r = 0; r < 4; ++r) {
        int row = mt * 16 + quad * 4 + r;
        float v = acc[r] + bsc;
        if constexpr (MODE == 2) {
          racc[(mt * 8 + nt) * 4 + r] += v;
        } else {
          if constexpr (MODE == 1) v += b2f(Res[row * ldr + n]);
          v = fmaxf(v, 0.f);
          Dst[row * ldd + n] = f2b(v);
        }
      }
    }
  }
  __syncthreads();
}

// ---- main: sample + PE + view MLP x4 + mean + global MLP -------------------
// Single-wave blocks: 4096 blocks x 64 threads, 32 points each. LDS 19.5 KB.
__global__ __launch_bounds__(64) void mvct_main(
    const float* __restrict__ angles, const int* __restrict__ idx,
    const unsigned short* __restrict__ wbuf,
    const float* __restrict__ vb_in, const float* __restrict__ vb1,
    const float* __restrict__ vb2, const float* __restrict__ vb_out,
    const float* __restrict__ gb_in, const float* __restrict__ gb1,
    const float* __restrict__ gb2, const float* __restrict__ gw_out,
    const float* __restrict__ gb_out,
    float* __restrict__ out)
{
  __shared__ __align__(16) unsigned short X[32][168];  // xin(160)/t(128)
  __shared__ __align__(16) unsigned short Hb[32][136]; // h
  const int lane = threadIdx.x;
  const int b = blockIdx.x >> 11;
  const int pts0 = (blockIdx.x & 2047) * 32;

  const unsigned short* w_in_t   = wbuf;
  const unsigned short* vw1_t    = wbuf + 20480;
  const unsigned short* vw2_t    = wbuf + 69632;
  const unsigned short* vw_out_t = wbuf + 118784;
  const unsigned short* gw_in_t  = wbuf + 135168;
  const unsigned short* gw1_t    = wbuf + 151552;
  const unsigned short* gw2_t    = wbuf + 184320;

  const float inv = 2.0f / 127.0f;
  const int pl = lane >> 4, cg = lane & 15;

  // PE into X cols 128..159 (never clobbered by the layer loop)
  if (lane < 32) {
    int id = idx[pts0 + lane];
    int iz = (id >> 14) & 127, iy = (id >> 7) & 127, ix = id & 127;
    float x = ix * inv - 1.f, y = iy * inv - 1.f, z = iz * inv - 1.f;
    const float PI = 3.14159265358979323846f;
    float pe[9] = {z, y, x, sinf(PI * z), sinf(PI * y), sinf(PI * x),
                   cosf(PI * z), cosf(PI * y), cosf(PI * x)};
#pragma unroll
    for (int j = 0; j < 9; ++j) X[lane][128 + j] = f2b(pe[j]);
    for (int j = 137; j < 160; ++j) X[lane][j] = 0;
  }
  __syncthreads();

  float racc[64];
#pragma unroll
  for (int i = 0; i < 64; ++i) racc[i] = 0.f;

#pragma unroll 1
  for (int v = 0; v < VV; ++v) {
    const int bv = b * VV + v;
    const float ang = angles[bv];
    const float ct = cosf(ang), st = sinf(ang);

    // bilinear gather of precomputed feats: 32 pts (4 pts/iter, 8 ch/lane)
    for (int it = 0; it < 8; ++it) {
      int lp = it * 4 + pl;
      int id = idx[pts0 + lp];
      int iz = (id >> 14) & 127, iy = (id >> 7) & 127, ix = id & 127;
      float x = ix * inv - 1.f, y = iy * inv - 1.f, z = iz * inv - 1.f;
      float u = x * ct - y * st;
      float px = (u + 1.f) * 127.5f, py = (z + 1.f) * 127.5f;
      px = fminf(fmaxf(px, 0.f), 255.f);
      py = fminf(fmaxf(py, 0.f), 255.f);
      int x0 = min((int)px, 254), y0 = min((int)py, 254);
      float wx = px - (float)x0, wy = py - (float)y0;
      const unsigned short* bp =
          g_feats + ((size_t)((bv * HH + y0) * WW + x0)) * CCH + cg * 8;
      ushort8 q00 = *(const ushort8*)bp;
      ushort8 q01 = *(const ushort8*)(bp + CCH);
      ushort8 q10 = *(const ushort8*)(bp + WW * CCH);
      ushort8 q11 = *(const ushort8*)(bp + WW * CCH + CCH);
      float w00 = (1.f - wx) * (1.f - wy), w01 = wx * (1.f - wy);
      float w10 = (1.f - wx) * wy, w11 = wx * wy;
      ushort8 o;
#pragma unroll
      for (int j = 0; j < 8; ++j) {
        float f = w00 * b2f(q00[j]) + w01 * b2f(q01[j]) +
                  w10 * b2f(q10[j]) + w11 * b2f(q11[j]);
        o[j] = f2b(f);
      }
      *(ushort8*)&X[lp][cg * 8] = o;
    }
    __syncthreads();

    mlp_layer<160, 0>(&X[0][0], 168, w_in_t, vb_in,
                      nullptr, 0, &Hb[0][0], 136, nullptr, lane);
#pragma unroll 1
    for (int i = 0; i < 3; ++i) {
      mlp_layer<128, 0>(&Hb[0][0], 136, vw1_t + i * 16384, vb1 + i * 128,
                        nullptr, 0, &X[0][0], 168, nullptr, lane);
      mlp_layer<128, 1>(&X[0][0], 168, vw2_t + i * 16384, vb2 + i * 128,
                        &Hb[0][0], 136, &Hb[0][0], 136, nullptr, lane);
    }
    mlp_layer<128, 2>(&Hb[0][0], 136, vw_out_t, vb_out,
                      nullptr, 0, nullptr, 0, racc, lane);
  }

  // mean over views -> X cols 0..127 (bf16)
  {
    const int col = lane & 15, quad = lane >> 4;
#pragma unroll
    for (int mt = 0; mt < 2; ++mt)
#pragma unroll
      for (int nt = 0; nt < 8; ++nt)
#pragma unroll
        for (int r = 0; r < 4; ++r)
          X[mt * 16 + quad * 4 + r][nt * 16 + col] =
              f2b(racc[(mt * 8 + nt) * 4 + r] * 0.25f);
  }
  __syncthreads();

  mlp_layer<128, 0>(&X[0][0], 168, gw_in_t, gb_in,
                    nullptr, 0, &Hb[0][0], 136, nullptr, lane);
#pragma unroll 1
  for (int i = 0; i < 2; ++i) {
    mlp_layer<128, 0>(&Hb[0][0], 136, gw1_t + i * 16384, gb1 + i * 128,
                      nullptr, 0, &X[0][0], 168, nullptr, lane);
    mlp_layer<128, 1>(&X[0][0], 168, gw2_t + i * 16384, gb2 + i * 128,
                      &Hb[0][0], 136, &Hb[0][0], 136, nullptr, lane);
  }

  // out = h @ gw_out + gb_out; 2 lanes per point; f32 output
  const int p = lane & 31, half = lane >> 5;
  float s = 0.f;
  const unsigned short* hr = &Hb[p][half * 64];
  const float* wo = gw_out + half * 64;
#pragma unroll
  for (int c = 0; c < 64; ++c)
    s += b2f(hr[c]) * wo[c];
  s += __shfl_xor(s, 32, 64);
  if (half == 0)
    out[(size_t)b * NPTSC + pts0 + p] = s + gb_out[0];
}

extern "C" void kernel_launch(void* const* d_in, const int* in_sizes, int n_in,
                              void* d_out, int out_size, void* d_ws, size_t ws_size,
                              hipStream_t stream) {
  const float* views  = (const float*)d_in[0];
  const float* angles = (const float*)d_in[1];
  const int*   idx    = (const int*)d_in[2];
  const float* conv_w = (const float*)d_in[3];
  const float* conv_b = (const float*)d_in[4];
  const float* vw_in  = (const float*)d_in[5];
  const float* vb_in  = (const float*)d_in[6];
  const float* vw1    = (const float*)d_in[7];
  const float* vb1    = (const float*)d_in[8];
  const float* vw2    = (const float*)d_in[9];
  const float* vb2    = (const float*)d_in[10];
  const float* vw_out = (const float*)d_in[11];
  const float* vb_out = (const float*)d_in[12];
  const float* gw_in  = (const float*)d_in[13];
  const float* gb_in  = (const float*)d_in[14];
  const float* gw1    = (const float*)d_in[15];
  const float* gb1    = (const float*)d_in[16];
  const float* gw2    = (const float*)d_in[17];
  const float* gb2    = (const float*)d_in[18];
  const float* gw_out = (const float*)d_in[19];
  const float* gb_out = (const float*)d_in[20];

  unsigned short* wbuf = (unsigned short*)d_ws;  // 434 KB

  hipLaunchKernelGGL(mvct_prep, dim3(848), dim3(256), 0, stream,
                     vw_in, vw1, vw2, vw_out, gw_in, gw1, gw2, wbuf);
  hipLaunchKernelGGL(mvct_conv, dim3(BB * VV * HH), dim3(128), 0, stream,
                     views, conv_w, conv_b);
  hipLaunchKernelGGL(mvct_main, dim3(BB * (NPTSC / 32)), dim3(64), 0, stream,
                     angles, idx, wbuf, vb_in, vb1, vb2, vb_out,
                     gb_in, gb1, gb2, gw_out, gb_out,
                     (float*)d_out);
}